// Round 20
// baseline (30.889 us; speedup 1.0000x reference)
//
#include <hip/hip_runtime.h>

// Lucas-Kanade optical flow v19b = v18 + phase-stagger (fixed: s_sleep needs
// a constant immediate -> constant-dispatch via switch on bid&7).
// Convoy theory: per-CU pipe times SUM (VMEM ~12us + DS ~10us + VALU ~8us
// ~= 30us observed) instead of overlapping, because all co-resident waves
// run the identical 22-step program in lockstep -> correlated bursts
// saturate one pipe at a time. Stagger block start by (bid&7)*~128cyc so
// bursts decorrelate; offsets persist through the kernel.
// Everything else is v18 verbatim (best, 30.6us): RB=8, 4864 one-wave
// blocks, E-depth 7, X-reload depth 5, pre-shuffled col-2 caches,
// prefix-doubling emit, 2 cols/lane, XCD swizzle, no occupancy attrs.
// Derivatives unscaled (8fx,8fy,4ft); exact x2 rescale folded into u,v.

constexpr int IH  = 2048;
constexpr int IW  = 2048;
constexpr int RAD = 7;
constexpr int WIN = 15;
constexpr int NT  = 64;               // 1 wave per block
constexpr int SW  = 112;              // output columns per block (2/lane, lanes 0..55)
constexpr int RB  = 8;                // output rows per block
constexpr int SCAN = RB + WIN - 1;    // 22 steps; entering product rows r0-7 .. r0+14
constexpr int NSTRIP = 19;            // 19*112 = 2128 >= 2048
constexpr int NBAND  = IH / RB;       // 256
constexpr int NXCD   = 8;
constexpr int CHUNK  = NBAND / NXCD;  // 32 bands per XCD per strip

// Per-row derived terms for this lane's 2 columns: sp = prev+next, dt = next-prev.
struct Row { float sp0, sp1, dt0, dt1; };

template<bool YE>
__device__ __forceinline__ Row load_row(const float* __restrict__ P,
                                        const float* __restrict__ N,
                                        int row, int pcb, bool lload) {
    if constexpr (YE) row = row < 0 ? 0 : (row > IH - 1 ? IH - 1 : row);
    float2 q = make_float2(0.f, 0.f), r = q;
    if (lload) {                       // false only for OOB lanes on edge strips
        const size_t off = (size_t)row * IW + pcb;
        q = *reinterpret_cast<const float2*>(P + off);   // 8B aligned (pcb even)
        r = *reinterpret_cast<const float2*>(N + off);
    }
    Row R;
    R.sp0 = q.x + r.x; R.dt0 = r.x - q.x;
    R.sp1 = q.y + r.y; R.dt1 = r.y - q.y;
    return R;
}

// Col-2 (neighbor-lane) terms for one row, shuffled ONCE at load/slide time.
struct Sh { float sp4, dt4; };

template<bool XE>
__device__ __forceinline__ Sh mksh(const Row& R, int t, bool rep2) {
    Sh s;
    s.sp4 = __shfl(R.sp0, t + 1);     // lane63 wrap feeds only untracked col
    s.dt4 = __shfl(R.dt0, t + 1);
    if constexpr (XE) {               // right edge: replicate own last column
        s.sp4 = rep2 ? R.sp1 : s.sp4;
        s.dt4 = rep2 ? R.dt1 : s.dt4;
    }
    return s;
}

// Add (SUB=false) or remove (SUB=true) product-row pair (A=row r, B=row r+1),
// with pre-shuffled col-2 terms for A and B.
template<bool SUB, bool XE>
__device__ __forceinline__ void accum(float V[5][2], const Row& A, const Row& B,
                                      const Sh& sa, const Sh& sb, bool ok) {
    const float g0 = A.sp0 + B.sp0, g1 = A.sp1 + B.sp1;  // -> 8*fx via horiz diff
    const float m0 = B.sp0 - A.sp0, m1 = B.sp1 - A.sp1;  // -> 8*fy
    const float e0 = A.dt0 + B.dt0, e1 = A.dt1 + B.dt1;  // -> 4*ft
    const float g2 = sa.sp4 + sb.sp4;                    // col-2 terms, no shfl
    const float m2 = sb.sp4 - sa.sp4;
    const float e2 = sa.dt4 + sb.dt4;
    float fx0 = g1 - g0, fy0 = m0 + m1, ft0 = e0 + e1;
    float fx1 = g2 - g1, fy1 = m1 + m2, ft1 = e1 + e2;
    if constexpr (XE) {                 // zero products outside the image
        fx0 = ok ? fx0 : 0.f; fy0 = ok ? fy0 : 0.f; ft0 = ok ? ft0 : 0.f;
        fx1 = ok ? fx1 : 0.f; fy1 = ok ? fy1 : 0.f; ft1 = ok ? ft1 : 0.f;
    }
    if constexpr (!SUB) {
        V[0][0] += fx0 * fx0; V[1][0] += fx0 * fy0; V[2][0] += fy0 * fy0;
        V[3][0] += fx0 * ft0; V[4][0] += fy0 * ft0;
        V[0][1] += fx1 * fx1; V[1][1] += fx1 * fy1; V[2][1] += fy1 * fy1;
        V[3][1] += fx1 * ft1; V[4][1] += fy1 * ft1;
    } else {
        V[0][0] -= fx0 * fx0; V[1][0] -= fx0 * fy0; V[2][0] -= fy0 * fy0;
        V[3][0] -= fx0 * ft0; V[4][0] -= fy0 * ft0;
        V[0][1] -= fx1 * fx1; V[1][1] -= fx1 * fy1; V[2][1] -= fy1 * fy1;
        V[3][1] -= fx1 * ft1; V[4][1] -= fy1 * ft1;
    }
}

template<bool XE, bool YE>
__device__ __forceinline__ void lk_body(const float* __restrict__ P,
                                        const float* __restrict__ N,
                                        float* __restrict__ out,
                                        int c0, int r0, int t) {
    const int pcb = c0 - 8 + 2 * t;     // lane's first tracked product column (even)
    bool ok = true, rep2 = false;
    if constexpr (XE) {
        ok   = ((unsigned)pcb < (unsigned)IW);   // both owned cols in image
        rep2 = (pcb + 2 >= IW) && ok;            // col pcb+2 replicates pcb+1
    }
    const bool lload = ok;              // interior strips: uniformly true

    float V[5][2] = {};

    // entering pipeline E0..E6 = rows r0-7 .. r0-1 (use distance 5-7 steps)
    Row E0 = load_row<YE>(P, N, r0 - 7, pcb, lload);
    Row E1 = load_row<YE>(P, N, r0 - 6, pcb, lload);
    Row E2 = load_row<YE>(P, N, r0 - 5, pcb, lload);
    Row E3 = load_row<YE>(P, N, r0 - 4, pcb, lload);
    Row E4 = load_row<YE>(P, N, r0 - 3, pcb, lload);
    Row E5 = load_row<YE>(P, N, r0 - 2, pcb, lload);
    Row E6 = load_row<YE>(P, N, r0 - 1, pcb, lload);
    Row X0, X1, X2, X3, X4;             // exit-reload pipeline, depth 5

    // pre-shuffled col-2 caches for the rows entering accum next
    Sh e0s = mksh<XE>(E0, t, rep2);
    Sh e1s = mksh<XE>(E1, t, rep2);
    Sh x0s, x1s;

    #pragma unroll
    for (int sr = 0; sr < SCAN; ++sr) { // fully unrolled: sr compile-time
        const int pr = r0 - RAD + sr;   // entering product row

        // deep prefetch: entering row pr+7 (last needed image row = r0+15)
        Row nE, nX;
        const bool doE = (sr <= 15);
        if (doE) nE = load_row<YE>(P, N, pr + 7, pcb, lload);
        const bool doX = (sr >= 10 && sr <= 17);  // row r0+sr-17: r0-7 .. r0
        if (doX) nX = load_row<YE>(P, N, r0 + sr - 17, pcb, lload);

        // add entering product row (rows pr = E0, pr+1 = E1)
        bool enter_ok = true;
        if constexpr (YE) enter_ok = (pr >= 0) && (pr < IH);
        if (enter_ok) accum<false, XE>(V, E0, E1, e0s, e1s, ok);
        // roll the enter shuffle-cache: next step's pair = (E1, E2)
        e0s = e1s; e1s = mksh<XE>(E2, t, rep2);

        // subtract exiting product row (rows pr-15 = X0, pr-14 = X1)
        if (sr >= WIN) {
            bool exit_ok = true;
            if constexpr (YE) exit_ok = (pr - WIN) >= 0;
            if (exit_ok) accum<true, XE>(V, X0, X1, x0s, x1s, ok);
        }
        // build/roll the exit shuffle-cache (X0 set at sr=10, X1 at 11, ...)
        if (sr == 13)      x0s = mksh<XE>(X0, t, rep2);
        else if (sr == 14) x1s = mksh<XE>(X1, t, rep2);
        else if (sr >= 15 && sr < SCAN - 1) { x0s = x1s; x1s = mksh<XE>(X2, t, rep2); }

        // emit output row i = r0 + sr - 14
        if (sr >= WIN - 1) {
            float a0[5], a1[5];
            #pragma unroll
            for (int p = 0; p < 5; ++p) {
                const float Pg = V[p][0] + V[p][1];        // pair sum (2 cols)
                float S = Pg + __shfl(Pg, t + 1);
                S += __shfl(S, t + 2);
                S += __shfl(S, t + 4);                     // cols pcb..pcb+15
                const float q0 = __shfl(V[p][0], t + 8);   // col pcb+16
                a0[p] = S - V[p][0];                       // cols pcb+1 .. pcb+15
                a1[p] = (S - Pg) + q0;                     // cols pcb+2 .. pcb+16
            }
            const float det0 = a0[0] * a0[2] - a0[1] * a0[1];
            const float rd0  = __builtin_amdgcn_rcpf(det0) * 2.0f;  // fold scale
            const bool  k0   = (det0 != 0.f);
            const float det1 = a1[0] * a1[2] - a1[1] * a1[1];
            const float rd1  = __builtin_amdgcn_rcpf(det1) * 2.0f;
            const bool  k1   = (det1 != 0.f);
            float2 qu, qv;
            qu.x = k0 ? (a0[2] * a0[3] - a0[1] * a0[4]) * rd0 : 0.f;
            qv.x = k0 ? (a0[0] * a0[4] - a0[1] * a0[3]) * rd0 : 0.f;
            qu.y = k1 ? (a1[2] * a1[3] - a1[1] * a1[4]) * rd1 : 0.f;
            qv.y = k1 ? (a1[0] * a1[4] - a1[1] * a1[3]) * rd1 : 0.f;

            const int i  = r0 + sr - (WIN - 1);
            const int x0 = c0 + 2 * t;
            if ((2 * t < SW) && (x0 < IW)) {   // x0 even -> x0+1 in range too
                *reinterpret_cast<float2*>(out + (size_t)i * IW + x0) = qu;
                *reinterpret_cast<float2*>(out + (size_t)IH * IW + (size_t)i * IW + x0) = qv;
            }
        }

        // slides (register renames after full unroll)
        E0 = E1; E1 = E2; E2 = E3; E3 = E4; E4 = E5; E5 = E6; if (doE) E6 = nE;
        if (sr == 10)      X0 = nX;
        else if (sr == 11) X1 = nX;
        else if (sr == 12) X2 = nX;
        else if (sr == 13) X3 = nX;
        else if (sr == 14) X4 = nX;
        else if (sr >= 15) { X0 = X1; X1 = X2; X2 = X3; X3 = X4; if (sr <= 17) X4 = nX; }
    }
}

__global__ __launch_bounds__(NT)   // NO occupancy attrs: they pin VGPR=64 and spill
void lk_kernel(const float* __restrict__ Pimg, const float* __restrict__ Nimg,
               float* __restrict__ out) {
    // Phase stagger: co-resident blocks sleep 0..7 x ~128cyc so their
    // load/VALU/DS bursts interleave across pipes instead of convoying.
    // s_sleep requires a constant immediate -> constant-dispatch switch.
    // (s_sleep N sleeps ~N*64 cycles; max 7*2*64 ~= 900 cyc ~ 1% of runtime.)
    switch (blockIdx.x & 7) {
        case 0: break;
        case 1: __builtin_amdgcn_s_sleep(2);  break;
        case 2: __builtin_amdgcn_s_sleep(4);  break;
        case 3: __builtin_amdgcn_s_sleep(6);  break;
        case 4: __builtin_amdgcn_s_sleep(8);  break;
        case 5: __builtin_amdgcn_s_sleep(10); break;
        case 6: __builtin_amdgcn_s_sleep(12); break;
        default: __builtin_amdgcn_s_sleep(14); break;
    }

    // XCD-chunked swizzle: XCD (bid&7) owns 32 contiguous 8-row bands of one
    // strip -> vertical-halo re-reads hit the local L2.
    const int bid   = blockIdx.x;
    const int xcd   = bid & 7;
    const int idx   = bid >> 3;               // 0..607
    const int strip = idx / CHUNK;            // 0..18
    const int pos   = idx % CHUNK;
    const int band  = xcd * CHUNK + pos;      // 0..255
    const int c0 = strip * SW;
    const int r0 = band * RB;
    const int t  = threadIdx.x;
    const bool xe = (strip == 0) || (strip == NSTRIP - 1);
    // rows touched: [r0-7, r0+15]; in-bounds iff 1 <= band <= NBAND-2
    const bool ye = (band == 0) || (band == NBAND - 1);
    if (!xe && !ye)      lk_body<false, false>(Pimg, Nimg, out, c0, r0, t);
    else if (xe && !ye)  lk_body<true,  false>(Pimg, Nimg, out, c0, r0, t);
    else if (!xe)        lk_body<false, true >(Pimg, Nimg, out, c0, r0, t);
    else                 lk_body<true,  true >(Pimg, Nimg, out, c0, r0, t);
}

extern "C" void kernel_launch(void* const* d_in, const int* in_sizes, int n_in,
                              void* d_out, int out_size, void* d_ws, size_t ws_size,
                              hipStream_t stream) {
    (void)in_sizes; (void)n_in; (void)d_ws; (void)ws_size; (void)out_size;
    const float* prev = (const float*)d_in[0];
    const float* nxt  = (const float*)d_in[1];
    float* out        = (float*)d_out;
    dim3 grid(NSTRIP * NBAND);                // 4864 one-wave blocks
    dim3 block(NT);
    hipLaunchKernelGGL(lk_kernel, grid, block, 0, stream, prev, nxt, out);
}